// Round 1
// baseline (317.521 us; speedup 1.0000x reference)
//
#include <hip/hip_runtime.h>
#include <hip/hip_bf16.h>

// Problem dims (hard-coded from reference)
#define N_B   32
#define C_IN  150
#define HH    56
#define WW    56
#define O_P   225
#define D_F   1350   // C_IN * 9
#define SPLIT 75

// Padded dims for MFMA
#define C_PAD 160    // K padded to 5 chunks of 32
#define O_PAD 256    // O padded to 16 tiles of 16
#define PSTR  168    // LDS position stride (elements); 336B => conflict-spread b128 reads
#define NPLANE 58    // positions -1..56 => 58

typedef __attribute__((ext_vector_type(8))) short short8;  // 8 bf16 = 4 VGPR
typedef __attribute__((ext_vector_type(4))) float f32x4;
typedef unsigned short ushort_t;
typedef unsigned int uint_t;

// Workspace layout (bytes). Total ~33.66 MB.
#define XT_OFF 0                           // x_t bf16 NHWC: 32*56*56*160*2 = 32,112,640
#define WT_OFF 32112640                    // Wt bf16 [9][256][160]*2      =    737,280
#define P2_OFF (WT_OFF + 737280)           // p2 fp32 [256]                =      1,024
#define SQ_OFF (P2_OFF + 1024)             // sq fp32 [32*3136]            =    401,408
#define X2_OFF (SQ_OFF + 401408)           // x2 fp32 [32*3136]            =    401,408

__device__ __forceinline__ ushort_t f2bf(float f) {
  uint_t u = __builtin_bit_cast(uint_t, f);
  u += 0x7fffu + ((u >> 16) & 1u);   // RNE
  return (ushort_t)(u >> 16);
}

// ---------------------------------------------------------------------------
// Kernel 1: NCHW fp32 -> NHWC bf16 (C padded to 160, zeros), plus
// sq[n,h,w] = sum_c wc * x^2 (fp32) for the x2 term.
// ---------------------------------------------------------------------------
__global__ __launch_bounds__(256) void prep_x(const float* __restrict__ x,
                                              ushort_t* __restrict__ xt,
                                              float* __restrict__ sq) {
  __shared__ float tile[C_IN][WW + 1];   // +1 pad: conflict-free transposed reads
  const int n = blockIdx.y, h = blockIdx.x, tid = threadIdx.x;

  for (int idx = tid; idx < C_IN * WW; idx += 256) {
    int c = idx / WW, w = idx % WW;
    tile[c][w] = x[((n * C_IN + c) * HH + h) * WW + w];   // coalesced in w
  }
  __syncthreads();

  // packed bf16x2 writes, coalesced in c
  uint_t* xt32 = (uint_t*)(xt + (size_t)((n * HH + h) * WW) * C_PAD);
  for (int idx = tid; idx < WW * (C_PAD / 2); idx += 256) {
    int w = idx / (C_PAD / 2), c2 = idx % (C_PAD / 2), c = 2 * c2;
    float f0 = (c     < C_IN) ? tile[c][w]     : 0.f;
    float f1 = (c + 1 < C_IN) ? tile[c + 1][w] : 0.f;
    (void)w;
    xt32[idx] = (uint_t)f2bf(f0) | ((uint_t)f2bf(f1) << 16);
  }

  if (tid < WW) {
    float s = 0.f;
    for (int c = 0; c < C_IN; ++c) {
      float v = tile[c][tid];
      s += ((c < SPLIT) ? 0.25f : 0.75f) * v * v;
    }
    sq[(n * HH + h) * WW + tid] = s;
  }
}

// ---------------------------------------------------------------------------
// Kernel 2: weights -> per-tap bf16 [t][o_pad][c_pad] scaled by wc, plus
// p2[o] = sum_d wfull_d * weight^2 (fp32).
// ---------------------------------------------------------------------------
__global__ __launch_bounds__(256) void prep_w(const float* __restrict__ wgt,
                                              ushort_t* __restrict__ wt,
                                              float* __restrict__ p2) {
  const int o = blockIdx.x, tid = threadIdx.x;

  for (int idx = tid; idx < 9 * C_PAD; idx += 256) {
    int t = idx / C_PAD, c = idx % C_PAD;
    float v = 0.f;
    if (o < O_P && c < C_IN)
      v = wgt[o * D_F + c * 9 + t] * ((c < SPLIT) ? 0.25f : 0.75f);
    wt[(size_t)(t * O_PAD + o) * C_PAD + c] = f2bf(v);
  }

  float s = 0.f;
  if (o < O_P)
    for (int d = tid; d < D_F; d += 256) {
      float v = wgt[o * D_F + d];
      s += ((d / 9 < SPLIT) ? 0.25f : 0.75f) * v * v;
    }
  __shared__ float red[256];
  red[tid] = s;
  __syncthreads();
  for (int off = 128; off > 0; off >>= 1) {
    if (tid < off) red[tid] += red[tid + off];
    __syncthreads();
  }
  if (tid == 0) p2[o] = red[0];
}

// ---------------------------------------------------------------------------
// Kernel 3: x2 = 3x3 zero-padded box sum of sq (fp32, tiny, L2-resident)
// ---------------------------------------------------------------------------
__global__ __launch_bounds__(64) void box3(const float* __restrict__ sq,
                                           float* __restrict__ x2) {
  const int n = blockIdx.y, h = blockIdx.x, w = threadIdx.x;
  if (w >= WW) return;
  float s = 0.f;
  for (int dh = -1; dh <= 1; ++dh) {
    int hh = h + dh;
    if (hh < 0 || hh >= HH) continue;
    for (int dw = -1; dw <= 1; ++dw) {
      int ww2 = w + dw;
      if (ww2 < 0 || ww2 >= WW) continue;
      s += sq[(n * HH + hh) * WW + ww2];
    }
  }
  x2[(n * HH + h) * WW + w] = s;
}

// ---------------------------------------------------------------------------
// Kernel 4: main implicit-GEMM conv. Block = (n, h) output row.
// LDS holds rows h-1..h+1 (halo + zero borders), single barrier.
// Wave = 4 o-tiles x 4 w-tiles of 16x16x32 bf16 MFMA; 9 taps x 5 K-chunks.
// Epilogue: dist = sqrt(max(x2 + p2 - 2*xp, 1e-12)) -> NOHW.
// ---------------------------------------------------------------------------
__global__ __launch_bounds__(256, 2) void sfm_main(
    const ushort_t* __restrict__ xt, const ushort_t* __restrict__ wt,
    const float* __restrict__ p2g, const float* __restrict__ x2g,
    float* __restrict__ out) {
  // +8 slack rows: padding-column reads (w>=56, masked at store) stay in-bounds
  __shared__ __align__(16) ushort_t xtile[(3 * NPLANE + 8) * PSTR];
  __shared__ float p2s[O_PAD];
  __shared__ float x2row[64];

  const int n = blockIdx.y, h = blockIdx.x, tid = threadIdx.x;
  const int lane = tid & 63, wv = tid >> 6;

  // stage 3 planes (h-1..h+1), 16B chunks; 20 chunks per position (160 bf16)
  for (int idx = tid; idx < 3 * WW * 20; idx += 256) {
    int dh = idx / (WW * 20);
    int rem = idx % (WW * 20);
    int w = rem / 20, c8 = rem % 20;
    int hh = h + dh - 1;
    uint4 v = make_uint4(0u, 0u, 0u, 0u);
    if (hh >= 0 && hh < HH)
      v = *(const uint4*)(xt + ((size_t)((n * HH + hh) * WW + w) * C_PAD + c8 * 8));
    *(uint4*)(&xtile[(dh * NPLANE + (w + 1)) * PSTR + c8 * 8]) = v;
  }
  // zero halo columns (pos 0 = col -1, pos 57 = col 56)
  for (int idx = tid; idx < 120; idx += 256) {
    int dh = idx / 40, r = idx % 40, side = r / 20, c8 = r % 20;
    int pos = side ? 57 : 0;
    *(uint4*)(&xtile[(dh * NPLANE + pos) * PSTR + c8 * 8]) = make_uint4(0u, 0u, 0u, 0u);
  }
  if (tid < WW) x2row[tid] = x2g[(n * HH + h) * WW + tid];
  p2s[tid] = (tid < O_P) ? p2g[tid] : 0.f;
  __syncthreads();

  const int olo = lane & 15, quad = lane >> 4;
  f32x4 zero4 = {0.f, 0.f, 0.f, 0.f};
  f32x4 acc[4][4];
#pragma unroll
  for (int j = 0; j < 4; ++j)
#pragma unroll
    for (int i = 0; i < 4; ++i) acc[j][i] = zero4;

  for (int t = 0; t < 9; ++t) {
    const int dh = t / 3, dwo = t % 3;
#pragma unroll
    for (int kc = 0; kc < 5; ++kc) {
      const int c0 = kc * 32 + quad * 8;   // lane's 8 contiguous K elements
      short8 af[4], bf[4];
#pragma unroll
      for (int j = 0; j < 4; ++j) {
        int o = (wv * 4 + j) * 16 + olo;   // A row = o
        af[j] = *(const short8*)(wt + ((size_t)(t * O_PAD + o) * C_PAD + c0));
      }
#pragma unroll
      for (int i = 0; i < 4; ++i) {
        int pos = i * 16 + olo + dwo;      // B col = w; image col = w+dwo-1 -> pos w+dwo
        bf[i] = *(const short8*)(&xtile[(dh * NPLANE + pos) * PSTR + c0]);
      }
#pragma unroll
      for (int j = 0; j < 4; ++j)
#pragma unroll
        for (int i = 0; i < 4; ++i)
          acc[j][i] = __builtin_amdgcn_mfma_f32_16x16x32_bf16(af[j], bf[i], acc[j][i], 0, 0, 0);
    }
  }

  // epilogue: C/D layout col=lane&15 (w), row=quad*4+reg (o within tile)
#pragma unroll
  for (int j = 0; j < 4; ++j) {
    int ob = (wv * 4 + j) * 16 + quad * 4;
#pragma unroll
    for (int i = 0; i < 4; ++i) {
      int w = i * 16 + olo;
      if (w >= WW) continue;
#pragma unroll
      for (int r = 0; r < 4; ++r) {
        int o = ob + r;
        if (o < O_P) {
          float d2 = x2row[w] + p2s[o] - 2.f * acc[j][i][r];
          out[((size_t)(n * O_P + o) * HH + h) * WW + w] = sqrtf(fmaxf(d2, 1e-12f));
        }
      }
    }
  }
}

// ---------------------------------------------------------------------------
extern "C" void kernel_launch(void* const* d_in, const int* in_sizes, int n_in,
                              void* d_out, int out_size, void* d_ws, size_t ws_size,
                              hipStream_t stream) {
  const float* x      = (const float*)d_in[0];   // (32,150,56,56) fp32
  const float* weight = (const float*)d_in[1];   // (225,1350) fp32
  float* out = (float*)d_out;                    // (32,225,56,56) fp32
  char* ws = (char*)d_ws;                        // needs ~33.66 MB

  ushort_t* xt = (ushort_t*)(ws + XT_OFF);
  ushort_t* wt = (ushort_t*)(ws + WT_OFF);
  float* p2 = (float*)(ws + P2_OFF);
  float* sq = (float*)(ws + SQ_OFF);
  float* x2 = (float*)(ws + X2_OFF);

  prep_x<<<dim3(HH, N_B), 256, 0, stream>>>(x, xt, sq);
  prep_w<<<dim3(O_PAD), 256, 0, stream>>>(weight, wt, p2);
  box3<<<dim3(HH, N_B), 64, 0, stream>>>(sq, x2);
  sfm_main<<<dim3(HH, N_B), 256, 0, stream>>>(xt, wt, p2, x2, out);
}